// Round 1
// baseline (363.471 us; speedup 1.0000x reference)
//
#include <hip/hip_runtime.h>

// Problem constants (fixed by the reference file).
#define N_NODES 8192
#define DIM     256
#define NH      64
#define DEG     32
#define G       16     // nodes per QKV block (16 nodes, 4 waves: 2 node-groups x 2 split-K)

// Kernel T: one-time weight transpose into coalesced-load layout.
// WT[c4*64 + t] (float4) = W[t][4*c4 .. 4*c4+3].
// 3 mats x 4096 float4 = 12288 threads. Gather reads are fine: spread over
// 24 blocks -> ~512 line-transactions per CU, ~0.2 us total.
__global__ __launch_bounds__(512) void transpose_w(
    const float* __restrict__ Wq, const float* __restrict__ Wk,
    const float* __restrict__ Wv, float4* __restrict__ WT)
{
    const int tid = blockIdx.x * 512 + threadIdx.x;   // 0..12287
    const int mat = tid >> 12;                        // /4096
    const int r   = tid & 4095;                       // c4*64 + t
    const float4* src = (const float4*)(mat == 0 ? Wq : (mat == 1 ? Wk : Wv));
    WT[tid] = src[(r & 63) * 64 + (r >> 6)];          // in4[t*64 + c4]
}

// Kernel A: QKV projection. G=16 nodes per 256-thread (4-wave) block.
// Waves: pr = node-group (nodes pr*8..pr*8+7), kw = split-K half.
// Weight loads now COALESCED from the pre-transposed WT (lane t reads
// consecutive 16B -> 16 lines/instr vs 64 for the old row-gather), and
// G=16 halves per-weight L2 traffic to (N/16)*192KB = 96 MB.
// Cross-wave partials go through LDS indexed by ABSOLUTE node slot;
// the 4 waves write disjoint slot ranges (pair partner's store slots).
__global__ __launch_bounds__(256) void qkv_kernel(
    const float* __restrict__ x,
    const float4* __restrict__ WTq, const float4* __restrict__ WTk,
    const float4* __restrict__ WTv,
    const float* __restrict__ bq, const float* __restrict__ bk,
    float* __restrict__ Q, float* __restrict__ K, float* __restrict__ V)
{
    const int g0 = blockIdx.x * G;        // first node of this block
    const int t  = threadIdx.x & 63;      // 0..63 = output dim
    const int w  = threadIdx.x >> 6;      // wave id: 0..3
    const int kw = w & 1;                 // split-K half
    const int pr = w >> 1;                // node group: slots pr*8 .. pr*8+7

    __shared__ float xs[G * DIM];         // 16 KB: 16 x-rows
    __shared__ float red[3][G][64];       // 12 KB: cross-wave partials by slot

    // Stage 16 x-rows: 4096 floats = 1024 float4; 4 per thread, coalesced.
    const float4* xin = (const float4*)(x + (size_t)g0 * DIM);
    float4* xs4 = (float4*)xs;
    #pragma unroll
    for (int c = 0; c < (G * DIM / 4) / 256; ++c)
        xs4[threadIdx.x + 256 * c] = xin[threadIdx.x + 256 * c];
    __syncthreads();

    const int c0 = kw * 32;               // this wave's K-half (float4 index)
    const float4* wq = WTq + c0 * 64 + t; // coalesced: lanes read consecutive f4
    const float4* wk = WTk + c0 * 64 + t;
    const float4* wv = WTv + c0 * 64 + t;
    const int s0 = pr * 8;                // first slot of this wave's node group

    float accq[8], acck[8], accv[8];
    #pragma unroll
    for (int m = 0; m < 8; ++m) { accq[m] = 0.f; acck[m] = 0.f; accv[m] = 0.f; }

    #pragma unroll 4
    for (int c = 0; c < 32; ++c) {        // 32 iterations per wave (half of K)
        const float4 aq = wq[c * 64];
        const float4 ak = wk[c * 64];
        const float4 av = wv[c * 64];
        #pragma unroll
        for (int m = 0; m < 8; ++m) {
            // wave-uniform address -> LDS broadcast, no bank conflicts
            const float4 xv = ((const float4*)(xs + (s0 + m) * DIM))[c0 + c];
            accq[m] += xv.x * aq.x + xv.y * aq.y + xv.z * aq.z + xv.w * aq.w;
            acck[m] += xv.x * ak.x + xv.y * ak.y + xv.z * ak.z + xv.w * ak.w;
            accv[m] += xv.x * av.x + xv.y * av.y + xv.z * av.z + xv.w * av.w;
        }
    }

    // Publish partials for the pair-partner wave's store slots.
    // (pr,kw) writes slots pr*8 + (1-kw)*4 .. +4 -> the 4 waves write
    // disjoint ranges: w0:4..7, w1:0..3, w2:12..15, w3:8..11.
    const int other0 = s0 + (1 - kw) * 4;
    #pragma unroll
    for (int m = 0; m < 4; ++m) {
        const int li = (1 - kw) * 4 + m;  // local acc index for slot other0+m
        red[0][other0 + m][t] = accq[li];
        red[1][other0 + m][t] = acck[li];
        red[2][other0 + m][t] = accv[li];
    }
    __syncthreads();

    const float bqv = bq[t];
    const float bkv = bk[t];
    const int mine0 = s0 + kw * 4;        // this wave stores these 4 slots
    #pragma unroll
    for (int m = 0; m < 4; ++m) {
        const int slot = mine0 + m;
        const int li   = kw * 4 + m;      // local acc index for slot
        const int o = (g0 + slot) * NH + t;       // coalesced per m
        Q[o] = accq[li] + red[0][slot][t] + bqv;
        K[o] = acck[li] + red[1][slot][t] + bkv;
        V[o] = accv[li] + red[2][slot][t];
    }
}

// Kernel B: sparse attention over the 32 neighbors of each node.
// One wave per node. Lanes 0..31: score for neighbor j = (Q_i . K_j + ek)/512
// (the reference's /H then /sqrt(H), H=64). 64-lane shuffle softmax
// (inactive lanes carry -1e30 -> exp == 0). Neighbor ids and probabilities
// broadcast lane->wave via __shfl. Then all 64 lanes accumulate
// O[i][t] = sum_j p_j * V[nbr_j][t] (coalesced 256B per neighbor).
__global__ __launch_bounds__(64) void attn_kernel(
    const float* __restrict__ Q, const float* __restrict__ K,
    const float* __restrict__ V,
    const int* __restrict__ edge_dst,     // [E]; node i owns e = i*DEG .. +DEG-1
    const int* __restrict__ edge_type,    // [E]
    const float* __restrict__ ektab,      // [NTYPES]
    float* __restrict__ out)              // [N, NH] f32
{
    const int i = blockIdx.x;
    const int t = threadIdx.x;            // 0..63

    __shared__ float qs[NH];
    qs[t] = Q[i * NH + t];
    __syncthreads();                      // single-wave block: cheap

    float s = -1e30f;
    int nbr = 0;
    if (t < DEG) {
        const int e = i * DEG + t;
        nbr = edge_dst[e];
        const float ek = ektab[edge_type[e]];
        const float4* kr = (const float4*)(K + (size_t)nbr * NH);
        const float4* q4 = (const float4*)qs;
        float acc = 0.f;
        #pragma unroll
        for (int d = 0; d < NH / 4; ++d) {
            const float4 kv = kr[d];
            const float4 qv = q4[d];      // uniform address -> broadcast
            acc += qv.x * kv.x + qv.y * kv.y + qv.z * kv.z + qv.w * kv.w;
        }
        s = (acc + ek) * (1.0f / 512.0f);   // /H then /sqrt(H): 64*8
    }

    // wave softmax across 64 lanes (lanes >= DEG contribute exp -> 0)
    float m = s;
    #pragma unroll
    for (int off = 32; off > 0; off >>= 1) m = fmaxf(m, __shfl_xor(m, off));
    float p = __expf(s - m);
    float l = p;
    #pragma unroll
    for (int off = 32; off > 0; off >>= 1) l += __shfl_xor(l, off);
    p /= l;

    float o = 0.f;
    #pragma unroll 8
    for (int j = 0; j < DEG; ++j) {
        const float pj = __shfl(p, j);          // lane j holds neighbor j's prob
        const int   nj = __shfl(nbr, j);
        o += pj * V[(size_t)nj * NH + t];
    }

    out[i * NH + t] = o;
}

extern "C" void kernel_launch(void* const* d_in, const int* in_sizes, int n_in,
                              void* d_out, int out_size, void* d_ws, size_t ws_size,
                              hipStream_t stream) {
    // setup_inputs order (all floats f32 per the reference):
    // 0:x [N,D]  1:adj [N,N] (UNUSED)  2:edge_index [2,E] i32
    // 3:edge_type [E] i32  4:Wq [H,D]  5:bq [H]  6:Wk  7:bk  8:Wv
    // 9:edge_k_table [16,1]
    const float* x     = (const float*)d_in[0];
    const int*   eidx  = (const int*)d_in[2];
    const int*   etyp  = (const int*)d_in[3];
    const float* Wq    = (const float*)d_in[4];
    const float* bq    = (const float*)d_in[5];
    const float* Wk    = (const float*)d_in[6];
    const float* bk    = (const float*)d_in[7];
    const float* Wv    = (const float*)d_in[8];
    const float* ektab = (const float*)d_in[9];
    float*       out   = (float*)d_out;

    const int E = in_sizes[2] / 2;        // 262144

    float* Q = (float*)d_ws;              // [N, NH] f32
    float* K = Q + (size_t)N_NODES * NH;
    float* V = K + (size_t)N_NODES * NH;  // 6 MB of ws
    float4* WT = (float4*)(V + (size_t)N_NODES * NH);  // +192 KB: WTq|WTk|WTv

    transpose_w<<<dim3(24), dim3(512), 0, stream>>>(Wq, Wk, Wv, WT);
    qkv_kernel<<<dim3(N_NODES / G), dim3(256), 0, stream>>>(
        x, WT, WT + 4096, WT + 8192, bq, bk, Q, K, V);
    attn_kernel<<<dim3(N_NODES), dim3(64), 0, stream>>>(Q, K, V, eidx + E, etyp, ektab, out);
}